// Round 1
// baseline (512.358 us; speedup 1.0000x reference)
//
#include <hip/hip_runtime.h>
#include <hip/hip_bf16.h>

// SupernodePooling, restructured:
//   x = feat@W_in + b_in + sincos(pos)            [N,192]   (never materialized)
//   a = x @ W1_top                                [N,192]   bf16 in ws
//   b = x[sup] @ W1_bot + b1                      [S,192]   f32 in ws
//   g[s] = mean_{e in 32 edges of s} gelu(a[src_e] + b[s])  [S,192] f32 in ws
//   out = g @ W2 + b2                             [S,192]   f32
// Valid because concat-GEMM splits and segment-mean commutes with W2.
// Edge e belongs to segment e/32 (dst_idx = repeat(sorted supernode_idxs, 32)).

#define HD 192
#define INF 16
#define N_NODES 262144
#define N_SUP 16384

__device__ __forceinline__ unsigned f2bf(float f) {
    unsigned x = __float_as_uint(f);
    return (x + 0x7fffu + ((x >> 16) & 1u)) >> 16;   // RNE to bf16
}

// ---------------------------------------------------------------------------
// Fused: compute x rows for a 64-row tile (proj + sincos) into LDS, then
// tile @ W[192,192] (+bias) -> out (bf16 or f32).
// GATHER: row -> node id via gidx (supernode path); else node = row.
// ---------------------------------------------------------------------------
template<bool GATHER, bool OUT_BF16, bool HAS_BIAS>
__global__ __launch_bounds__(256, 2)
void x_gemm_kernel(const float* __restrict__ feat,   // [N,16]
                   const float* __restrict__ pos,    // [N,3]
                   const int*   __restrict__ gidx,   // [rows] or null
                   const float* __restrict__ Win,    // [16,192]
                   const float* __restrict__ bin,    // [192]
                   const float* __restrict__ W,      // [192,192] row-major
                   const float* __restrict__ bias,   // [192] or null
                   void* __restrict__ outp)
{
    __shared__ float xs[64][196];       // x tile, padded stride
    __shared__ float wchunk[32][HD];    // W k-chunk
    __shared__ float feat_s[64][INF];
    __shared__ float pos_s[64][3];
    __shared__ int   nid[64];

    const int t    = threadIdx.x;
    const int row0 = blockIdx.x * 64;

    if (t < 64) nid[t] = GATHER ? gidx[row0 + t] : (row0 + t);
    __syncthreads();

    // stage feat tile: 64x16 floats, thread t -> row t/4, quad t%4
    {
        const int i = t >> 2, q = t & 3;
        const float4* fp = reinterpret_cast<const float4*>(feat + (size_t)nid[i] * INF);
        *reinterpret_cast<float4*>(&feat_s[i][q * 4]) = fp[q];
    }
    if (t < 64) {
        const float* pp = pos + (size_t)nid[t] * 3;
        pos_s[t][0] = pp[0]; pos_s[t][1] = pp[1]; pos_s[t][2] = pp[2];
    }
    __syncthreads();

    // compute x[n][t] for this tile: input proj + sincos positional embed
    if (t < HD) {
        float winc[INF];
        #pragma unroll
        for (int k = 0; k < INF; ++k) winc[k] = Win[k * HD + t];
        const float binc = bin[t];
        const int   d  = t >> 6;          // coord index 0..2
        const int   j  = t & 63;          // within per-dim block
        const int   jj = j & 31;
        const bool  is_sin = (j < 32);
        // omega = 10000^(-jj/32) = exp2(-jj * log2(1e4)/32)
        const float omv = exp2f(-(float)jj * 0.41524101186098287f);
        for (int n = 0; n < 64; ++n) {
            const float ang = pos_s[n][d] * omv;
            const float pe  = is_sin ? __sinf(ang) : __cosf(ang);
            float acc = binc + pe;
            #pragma unroll
            for (int k = 0; k < INF; ++k) acc = fmaf(feat_s[n][k], winc[k], acc);
            xs[n][t] = acc;
        }
    }

    // GEMM phase: xs[64][192] @ W -> acc; thread tile 4 rows x 12 cols
    const int tr = t >> 4;    // 0..15 -> rows tr*4..tr*4+3
    const int tc = t & 15;    // 0..15 -> cols tc*12..tc*12+11
    float acc[4][12];
    #pragma unroll
    for (int i = 0; i < 4; ++i)
        #pragma unroll
        for (int j = 0; j < 12; ++j) acc[i][j] = 0.f;

    for (int kc = 0; kc < 6; ++kc) {
        __syncthreads();   // wchunk consumed (prev iter)
        {
            const float4* wp = reinterpret_cast<const float4*>(W + kc * 32 * HD);
            float4* wsp = reinterpret_cast<float4*>(&wchunk[0][0]);
            #pragma unroll
            for (int q = 0; q < 6; ++q) wsp[t + q * 256] = wp[t + q * 256];
        }
        __syncthreads();   // wchunk ready (also covers xs on kc==0)
        #pragma unroll 4
        for (int k = 0; k < 32; ++k) {
            const int kg = kc * 32 + k;
            float xv[4];
            #pragma unroll
            for (int i = 0; i < 4; ++i) xv[i] = xs[tr * 4 + i][kg];
            float wv[12];
            #pragma unroll
            for (int j4 = 0; j4 < 3; ++j4)
                *reinterpret_cast<float4*>(&wv[j4 * 4]) =
                    *reinterpret_cast<const float4*>(&wchunk[k][tc * 12 + j4 * 4]);
            #pragma unroll
            for (int i = 0; i < 4; ++i)
                #pragma unroll
                for (int j = 0; j < 12; ++j)
                    acc[i][j] = fmaf(xv[i], wv[j], acc[i][j]);
        }
    }

    float bb[12];
    #pragma unroll
    for (int j = 0; j < 12; ++j) bb[j] = HAS_BIAS ? bias[tc * 12 + j] : 0.f;

    #pragma unroll
    for (int i = 0; i < 4; ++i) {
        const size_t orow = (size_t)(row0 + tr * 4 + i);
        if (OUT_BF16) {
            unsigned* o = reinterpret_cast<unsigned*>(
                (__hip_bfloat16*)outp + orow * HD + tc * 12);
            #pragma unroll
            for (int m = 0; m < 6; ++m) {
                const float lo = acc[i][2 * m]     + bb[2 * m];
                const float hi = acc[i][2 * m + 1] + bb[2 * m + 1];
                o[m] = f2bf(lo) | (f2bf(hi) << 16);
            }
        } else {
            float* o = (float*)outp + orow * HD + tc * 12;
            #pragma unroll
            for (int j4 = 0; j4 < 3; ++j4) {
                float4 v;
                v.x = acc[i][j4 * 4 + 0] + bb[j4 * 4 + 0];
                v.y = acc[i][j4 * 4 + 1] + bb[j4 * 4 + 1];
                v.z = acc[i][j4 * 4 + 2] + bb[j4 * 4 + 2];
                v.w = acc[i][j4 * 4 + 3] + bb[j4 * 4 + 3];
                *reinterpret_cast<float4*>(o + j4 * 4) = v;
            }
        }
    }
}

// ---------------------------------------------------------------------------
// g[s] = (1/32) * sum_{e=0..31} gelu(a[src[s*32+e]] + b[s]),  exact gelu (erf)
// block = 192 threads covering 2 supernodes, ushort2 (2 cols) per thread
// ---------------------------------------------------------------------------
__global__ __launch_bounds__(192)
void pool_kernel(const __hip_bfloat16* __restrict__ a,  // [N,192] bf16
                 const float* __restrict__ b,           // [S,192]
                 const int* __restrict__ src_idx,       // [E]
                 float* __restrict__ g)                  // [S,192]
{
    __shared__ int sA[64];
    const int t = threadIdx.x;
    if (t < 64) sA[t] = src_idx[(size_t)blockIdx.x * 64 + t];
    __syncthreads();

    const int sl = t / 96;           // which of 2 supernodes
    const int c2 = t % 96;           // column pair
    const size_t s = (size_t)blockIdx.x * 2 + sl;
    const int* sp = sA + sl * 32;

    const float b0 = b[s * HD + 2 * c2];
    const float b1v = b[s * HD + 2 * c2 + 1];
    float acc0 = 0.f, acc1 = 0.f;
    #pragma unroll 4
    for (int e = 0; e < 32; ++e) {
        const int src = sp[e];
        const unsigned u = *reinterpret_cast<const unsigned*>(
            reinterpret_cast<const char*>(a) + (size_t)src * (HD * 2) + 4 * c2);
        const float v0 = __uint_as_float(u << 16) + b0;
        const float v1 = __uint_as_float(u & 0xffff0000u) + b1v;
        acc0 += 0.5f * v0 * (1.f + erff(v0 * 0.70710678118654752f));
        acc1 += 0.5f * v1 * (1.f + erff(v1 * 0.70710678118654752f));
    }
    float2 r; r.x = acc0 * 0.03125f; r.y = acc1 * 0.03125f;
    *reinterpret_cast<float2*>(g + s * HD + 2 * c2) = r;
}

// ---------------------------------------------------------------------------
// out = A[rows,192] @ W[192,192] + bias   (f32, A staged from global)
// ---------------------------------------------------------------------------
__global__ __launch_bounds__(256, 2)
void gemm192_kernel(const float* __restrict__ A,
                    const float* __restrict__ W,
                    const float* __restrict__ bias,
                    float* __restrict__ out)
{
    __shared__ float xs[64][196];
    __shared__ float wchunk[32][HD];
    const int t    = threadIdx.x;
    const int row0 = blockIdx.x * 64;

    const float4* ap = reinterpret_cast<const float4*>(A + (size_t)row0 * HD);
    #pragma unroll
    for (int q = 0; q < 12; ++q) {
        const int f4 = t + q * 256;           // 0..3071
        const int r = f4 / 48, c = f4 % 48;
        *reinterpret_cast<float4*>(&xs[r][c * 4]) = ap[f4];
    }

    const int tr = t >> 4;
    const int tc = t & 15;
    float acc[4][12];
    #pragma unroll
    for (int i = 0; i < 4; ++i)
        #pragma unroll
        for (int j = 0; j < 12; ++j) acc[i][j] = 0.f;

    for (int kc = 0; kc < 6; ++kc) {
        __syncthreads();
        {
            const float4* wp = reinterpret_cast<const float4*>(W + kc * 32 * HD);
            float4* wsp = reinterpret_cast<float4*>(&wchunk[0][0]);
            #pragma unroll
            for (int q = 0; q < 6; ++q) wsp[t + q * 256] = wp[t + q * 256];
        }
        __syncthreads();
        #pragma unroll 4
        for (int k = 0; k < 32; ++k) {
            const int kg = kc * 32 + k;
            float xv[4];
            #pragma unroll
            for (int i = 0; i < 4; ++i) xv[i] = xs[tr * 4 + i][kg];
            float wv[12];
            #pragma unroll
            for (int j4 = 0; j4 < 3; ++j4)
                *reinterpret_cast<float4*>(&wv[j4 * 4]) =
                    *reinterpret_cast<const float4*>(&wchunk[k][tc * 12 + j4 * 4]);
            #pragma unroll
            for (int i = 0; i < 4; ++i)
                #pragma unroll
                for (int j = 0; j < 12; ++j)
                    acc[i][j] = fmaf(xv[i], wv[j], acc[i][j]);
        }
    }

    float bb[12];
    #pragma unroll
    for (int j = 0; j < 12; ++j) bb[j] = bias[tc * 12 + j];

    #pragma unroll
    for (int i = 0; i < 4; ++i) {
        float* o = out + (size_t)(row0 + tr * 4 + i) * HD + tc * 12;
        #pragma unroll
        for (int j4 = 0; j4 < 3; ++j4) {
            float4 v;
            v.x = acc[i][j4 * 4 + 0] + bb[j4 * 4 + 0];
            v.y = acc[i][j4 * 4 + 1] + bb[j4 * 4 + 1];
            v.z = acc[i][j4 * 4 + 2] + bb[j4 * 4 + 2];
            v.w = acc[i][j4 * 4 + 3] + bb[j4 * 4 + 3];
            *reinterpret_cast<float4*>(o + j4 * 4) = v;
        }
    }
}

extern "C" void kernel_launch(void* const* d_in, const int* in_sizes, int n_in,
                              void* d_out, int out_size, void* d_ws, size_t ws_size,
                              hipStream_t stream)
{
    const float* feat = (const float*)d_in[0];
    const float* pos  = (const float*)d_in[1];
    const int*   sup  = (const int*)d_in[2];
    // d_in[3] batch_idx unused
    const int*   src  = (const int*)d_in[4];
    // d_in[5] dst_idx unused (segments are e/32 by construction)
    const float* Win  = (const float*)d_in[6];
    const float* bin  = (const float*)d_in[7];
    const float* W1   = (const float*)d_in[8];   // [384,192]
    const float* b1   = (const float*)d_in[9];
    const float* W2   = (const float*)d_in[10];  // [192,192]
    const float* b2   = (const float*)d_in[11];

    char* ws = (char*)d_ws;
    __hip_bfloat16* a = (__hip_bfloat16*)ws;                         // 100663296 B
    float* b  = (float*)(ws + 100663296);                            //  12582912 B
    float* g  = (float*)(ws + 100663296 + 12582912);                 //  12582912 B
    float* out = (float*)d_out;

    // a = x @ W1_top           (bf16 out, no bias)
    x_gemm_kernel<false, true, false><<<N_NODES / 64, 256, 0, stream>>>(
        feat, pos, nullptr, Win, bin, W1, nullptr, (void*)a);
    // b = x[sup] @ W1_bot + b1 (f32 out)
    x_gemm_kernel<true, false, true><<<N_SUP / 64, 256, 0, stream>>>(
        feat, pos, sup, Win, bin, W1 + 192 * HD, b1, (void*)b);
    // g = segment-mean(gelu(a[src] + b[dst]))
    pool_kernel<<<N_SUP / 2, 192, 0, stream>>>(a, b, src, g);
    // out = g @ W2 + b2
    gemm192_kernel<<<N_SUP / 64, 256, 0, stream>>>(g, W2, b2, out);
}

// Round 2
// 337.517 us; speedup vs baseline: 1.5180x; 1.5180x over previous
//
#include <hip/hip_runtime.h>
#include <hip/hip_bf16.h>

// SupernodePooling, restructured:
//   x = feat@W_in + b_in + sincos(pos)            [N,192]   (never materialized)
//   a = x @ W1_top                                [N,192]   bf16 in ws   (MFMA bf16)
//   b = x[sup] @ W1_bot + b1                      [S,192]   f32 in ws
//   g[s] = mean_{e in 32 edges of s} gelu(a[src_e] + b[s])  [S,192] f32 (in-place over b)
//   out = g @ W2 + b2                             [S,192]   f32
// Valid because concat-GEMM splits and segment-mean commutes with W2.
// Edge e belongs to segment e/32 (dst_idx = repeat(sorted supernode_idxs, 32)).

#define HD 192
#define INF 16
#define N_NODES 262144
#define N_SUP 16384
#define XS_STRIDE 232   // bf16 units; 464 B = 29*16 -> 16B-aligned rows, bank-spread

typedef __attribute__((ext_vector_type(8))) short bf16x8;
typedef __attribute__((ext_vector_type(4))) float f32x4;

__device__ __forceinline__ unsigned f2bf(float f) {
    unsigned x = __float_as_uint(f);
    return (x + 0x7fffu + ((x >> 16) & 1u)) >> 16;   // RNE to bf16
}

// ---------------------------------------------------------------------------
// prep: Wt[n][k] = bf16(W1_top[k][n])  (transpose so MFMA B-frag reads are
// contiguous-in-k), 36864 elems, 144 blocks x 256
// ---------------------------------------------------------------------------
__global__ void prep_wt_kernel(const float* __restrict__ W1,
                               __hip_bfloat16* __restrict__ Wt)
{
    const int i = blockIdx.x * 256 + threadIdx.x;   // i = n*192 + k
    const int n = i / HD, k = i % HD;
    reinterpret_cast<unsigned short*>(Wt)[i] = (unsigned short)f2bf(W1[k * HD + n]);
}

// ---------------------------------------------------------------------------
// a = bf16( x ) @ bf16( W1_top )  via mfma_f32_16x16x32_bf16
// block: 256 thr = 4 waves, 64 rows. Wave w: all 64 rows x cols [w*48, w*48+48).
// A-frag: lane holds row (l&15), k = (l>>4)*8 + i   (contiguous 8)
// B-frag: lane holds col (l&15), k = (l>>4)*8 + i
// D:      col = l&15, row = (l>>4)*4 + reg          (m89-verified layout)
// ---------------------------------------------------------------------------
__global__ __launch_bounds__(256)
void a_mfma_kernel(const float* __restrict__ feat,   // [N,16]
                   const float* __restrict__ pos,    // [N,3]
                   const float* __restrict__ Win,    // [16,192]
                   const float* __restrict__ bin,    // [192]
                   const __hip_bfloat16* __restrict__ Wt,  // [192 n][192 k] bf16
                   __hip_bfloat16* __restrict__ a)   // [N,192]
{
    __shared__ __align__(16) unsigned short xs[64 * XS_STRIDE];  // 29696 B
    __shared__ float feat_s[64][INF];                            // 4096 B
    __shared__ float pos_s[64][4];                               // 1024 B

    const int t = threadIdx.x;
    const int w = t >> 6;        // wave 0..3
    const int l = t & 63;        // lane
    const int row0 = blockIdx.x * 64;

    // --- B-frag preload (18 frags, live all kernel) ---
    bf16x8 bf[3][6];
    #pragma unroll
    for (int ct = 0; ct < 3; ++ct) {
        const int col = w * 48 + ct * 16 + (l & 15);
        const __hip_bfloat16* wp = Wt + (size_t)col * HD + (l >> 4) * 8;
        #pragma unroll
        for (int ks = 0; ks < 6; ++ks)
            bf[ct][ks] = *reinterpret_cast<const bf16x8*>(wp + ks * 32);
    }

    // --- stage feat/pos tile ---
    {
        const int i = t >> 2, q = t & 3;
        const float4* fp = reinterpret_cast<const float4*>(feat + (size_t)(row0 + i) * INF);
        *reinterpret_cast<float4*>(&feat_s[i][q * 4]) = fp[q];
    }
    if (t < 64) {
        const float* pp = pos + (size_t)(row0 + t) * 3;
        pos_s[t][0] = pp[0]; pos_s[t][1] = pp[1]; pos_s[t][2] = pp[2];
    }

    // --- per-lane Win columns: lane l owns cols {l, l+64, l+128}, one omega ---
    float win[3][INF];
    #pragma unroll
    for (int d = 0; d < 3; ++d)
        #pragma unroll
        for (int k = 0; k < INF; ++k)
            win[d][k] = Win[k * HD + l + 64 * d];
    float bcol[3];
    #pragma unroll
    for (int d = 0; d < 3; ++d) bcol[d] = bin[l + 64 * d];

    const float om = exp2f(-(float)(l & 31) * 0.41524101186098287f);
    const bool is_sin = (l < 32);

    __syncthreads();

    // --- x compute: wave w fills rows w*16 .. w*16+15, bf16 into xs ---
    for (int r = 0; r < 16; ++r) {
        const int n = w * 16 + r;
        const float4 p = *reinterpret_cast<const float4*>(&pos_s[n][0]);
        const float pc[3] = {p.x, p.y, p.z};
        float fr[INF];
        #pragma unroll
        for (int q = 0; q < 4; ++q)
            *reinterpret_cast<float4*>(&fr[q * 4]) =
                *reinterpret_cast<const float4*>(&feat_s[n][q * 4]);
        #pragma unroll
        for (int d = 0; d < 3; ++d) {
            const float ang = pc[d] * om;
            const float pe = is_sin ? __sinf(ang) : __cosf(ang);
            float acc = bcol[d] + pe;
            #pragma unroll
            for (int k = 0; k < INF; ++k) acc = fmaf(fr[k], win[d][k], acc);
            xs[n * XS_STRIDE + l + 64 * d] = (unsigned short)f2bf(acc);
        }
    }

    __syncthreads();

    // --- MFMA: 4 row-tiles x 3 col-tiles, K = 6 x 32 ---
    f32x4 acc[4][3];
    #pragma unroll
    for (int rt = 0; rt < 4; ++rt)
        #pragma unroll
        for (int ct = 0; ct < 3; ++ct)
            acc[rt][ct] = (f32x4){0.f, 0.f, 0.f, 0.f};

    #pragma unroll
    for (int ks = 0; ks < 6; ++ks) {
        bf16x8 af[4];
        #pragma unroll
        for (int rt = 0; rt < 4; ++rt)
            af[rt] = *reinterpret_cast<const bf16x8*>(
                &xs[(rt * 16 + (l & 15)) * XS_STRIDE + ks * 32 + (l >> 4) * 8]);
        #pragma unroll
        for (int rt = 0; rt < 4; ++rt)
            #pragma unroll
            for (int ct = 0; ct < 3; ++ct)
                acc[rt][ct] = __builtin_amdgcn_mfma_f32_16x16x32_bf16(
                    af[rt], bf[ct][ks], acc[rt][ct], 0, 0, 0);
    }

    __syncthreads();   // all A-frag reads done; reuse xs for D staging

    #pragma unroll
    for (int rt = 0; rt < 4; ++rt)
        #pragma unroll
        for (int ct = 0; ct < 3; ++ct) {
            const int col = w * 48 + ct * 16 + (l & 15);
            #pragma unroll
            for (int j = 0; j < 4; ++j) {
                const int row = rt * 16 + (l >> 4) * 4 + j;
                xs[row * XS_STRIDE + col] = (unsigned short)f2bf(acc[rt][ct][j]);
            }
        }

    __syncthreads();

    // --- coalesced bf16 store: 1536 x 16B chunks, 6 per thread ---
    #pragma unroll
    for (int i = 0; i < 6; ++i) {
        const int c = t + i * 256;
        const int r = c / 24, q = c % 24;
        const bf16x8 v = *reinterpret_cast<const bf16x8*>(&xs[r * XS_STRIDE + q * 8]);
        *reinterpret_cast<bf16x8*>(
            reinterpret_cast<unsigned short*>(a) + (size_t)(row0 + r) * HD + q * 8) = v;
    }
}

// ---------------------------------------------------------------------------
// fp32 path (kept for the tiny b = x[sup] @ W1_bot + b1 GEMM, S rows)
// ---------------------------------------------------------------------------
template<bool GATHER, bool OUT_BF16, bool HAS_BIAS>
__global__ __launch_bounds__(256, 2)
void x_gemm_kernel(const float* __restrict__ feat,
                   const float* __restrict__ pos,
                   const int*   __restrict__ gidx,
                   const float* __restrict__ Win,
                   const float* __restrict__ bin,
                   const float* __restrict__ W,
                   const float* __restrict__ bias,
                   void* __restrict__ outp)
{
    __shared__ float xs[64][196];
    __shared__ float wchunk[32][HD];
    __shared__ float feat_s[64][INF];
    __shared__ float pos_s[64][3];
    __shared__ int   nid[64];

    const int t    = threadIdx.x;
    const int row0 = blockIdx.x * 64;

    if (t < 64) nid[t] = GATHER ? gidx[row0 + t] : (row0 + t);
    __syncthreads();

    {
        const int i = t >> 2, q = t & 3;
        const float4* fp = reinterpret_cast<const float4*>(feat + (size_t)nid[i] * INF);
        *reinterpret_cast<float4*>(&feat_s[i][q * 4]) = fp[q];
    }
    if (t < 64) {
        const float* pp = pos + (size_t)nid[t] * 3;
        pos_s[t][0] = pp[0]; pos_s[t][1] = pp[1]; pos_s[t][2] = pp[2];
    }
    __syncthreads();

    if (t < HD) {
        float winc[INF];
        #pragma unroll
        for (int k = 0; k < INF; ++k) winc[k] = Win[k * HD + t];
        const float binc = bin[t];
        const int   d  = t >> 6;
        const int   j  = t & 63;
        const int   jj = j & 31;
        const bool  is_sin = (j < 32);
        const float omv = exp2f(-(float)jj * 0.41524101186098287f);
        for (int n = 0; n < 64; ++n) {
            const float ang = pos_s[n][d] * omv;
            const float pe  = is_sin ? __sinf(ang) : __cosf(ang);
            float acc = binc + pe;
            #pragma unroll
            for (int k = 0; k < INF; ++k) acc = fmaf(feat_s[n][k], winc[k], acc);
            xs[n][t] = acc;
        }
    }

    const int tr = t >> 4;
    const int tc = t & 15;
    float acc[4][12];
    #pragma unroll
    for (int i = 0; i < 4; ++i)
        #pragma unroll
        for (int j = 0; j < 12; ++j) acc[i][j] = 0.f;

    for (int kc = 0; kc < 6; ++kc) {
        __syncthreads();
        {
            const float4* wp = reinterpret_cast<const float4*>(W + kc * 32 * HD);
            float4* wsp = reinterpret_cast<float4*>(&wchunk[0][0]);
            #pragma unroll
            for (int q = 0; q < 6; ++q) wsp[t + q * 256] = wp[t + q * 256];
        }
        __syncthreads();
        #pragma unroll 4
        for (int k = 0; k < 32; ++k) {
            const int kg = kc * 32 + k;
            float xv[4];
            #pragma unroll
            for (int i = 0; i < 4; ++i) xv[i] = xs[tr * 4 + i][kg];
            float wv[12];
            #pragma unroll
            for (int j4 = 0; j4 < 3; ++j4)
                *reinterpret_cast<float4*>(&wv[j4 * 4]) =
                    *reinterpret_cast<const float4*>(&wchunk[k][tc * 12 + j4 * 4]);
            #pragma unroll
            for (int i = 0; i < 4; ++i)
                #pragma unroll
                for (int j = 0; j < 12; ++j)
                    acc[i][j] = fmaf(xv[i], wv[j], acc[i][j]);
        }
    }

    float bb[12];
    #pragma unroll
    for (int j = 0; j < 12; ++j) bb[j] = HAS_BIAS ? bias[tc * 12 + j] : 0.f;

    #pragma unroll
    for (int i = 0; i < 4; ++i) {
        const size_t orow = (size_t)(row0 + tr * 4 + i);
        if (OUT_BF16) {
            unsigned* o = reinterpret_cast<unsigned*>(
                (__hip_bfloat16*)outp + orow * HD + tc * 12);
            #pragma unroll
            for (int m = 0; m < 6; ++m) {
                const float lo = acc[i][2 * m]     + bb[2 * m];
                const float hi = acc[i][2 * m + 1] + bb[2 * m + 1];
                o[m] = f2bf(lo) | (f2bf(hi) << 16);
            }
        } else {
            float* o = (float*)outp + orow * HD + tc * 12;
            #pragma unroll
            for (int j4 = 0; j4 < 3; ++j4) {
                float4 v;
                v.x = acc[i][j4 * 4 + 0] + bb[j4 * 4 + 0];
                v.y = acc[i][j4 * 4 + 1] + bb[j4 * 4 + 1];
                v.z = acc[i][j4 * 4 + 2] + bb[j4 * 4 + 2];
                v.w = acc[i][j4 * 4 + 3] + bb[j4 * 4 + 3];
                *reinterpret_cast<float4*>(o + j4 * 4) = v;
            }
        }
    }
}

// ---------------------------------------------------------------------------
// g[s] = (1/32) * sum_e gelu(a[src] + b[s]);  g may alias b (read-before-write)
// ---------------------------------------------------------------------------
__global__ __launch_bounds__(192)
void pool_kernel(const __hip_bfloat16* __restrict__ a,
                 const float* __restrict__ b,
                 const int* __restrict__ src_idx,
                 float* __restrict__ g)
{
    __shared__ int sA[64];
    const int t = threadIdx.x;
    if (t < 64) sA[t] = src_idx[(size_t)blockIdx.x * 64 + t];
    __syncthreads();

    const int sl = t / 96;
    const int c2 = t % 96;
    const size_t s = (size_t)blockIdx.x * 2 + sl;
    const int* sp = sA + sl * 32;

    const float b0 = b[s * HD + 2 * c2];
    const float b1v = b[s * HD + 2 * c2 + 1];
    float acc0 = 0.f, acc1 = 0.f;
    #pragma unroll 4
    for (int e = 0; e < 32; ++e) {
        const int src = sp[e];
        const unsigned u = *reinterpret_cast<const unsigned*>(
            reinterpret_cast<const char*>(a) + (size_t)src * (HD * 2) + 4 * c2);
        const float v0 = __uint_as_float(u << 16) + b0;
        const float v1 = __uint_as_float(u & 0xffff0000u) + b1v;
        acc0 += 0.5f * v0 * (1.f + erff(v0 * 0.70710678118654752f));
        acc1 += 0.5f * v1 * (1.f + erff(v1 * 0.70710678118654752f));
    }
    float2 r; r.x = acc0 * 0.03125f; r.y = acc1 * 0.03125f;
    *reinterpret_cast<float2*>(g + s * HD + 2 * c2) = r;
}

// ---------------------------------------------------------------------------
// out = A[rows,192] @ W[192,192] + bias   (f32)
// ---------------------------------------------------------------------------
__global__ __launch_bounds__(256, 2)
void gemm192_kernel(const float* __restrict__ A,
                    const float* __restrict__ W,
                    const float* __restrict__ bias,
                    float* __restrict__ out)
{
    __shared__ float xs[64][196];
    __shared__ float wchunk[32][HD];
    const int t    = threadIdx.x;
    const int row0 = blockIdx.x * 64;

    const float4* ap = reinterpret_cast<const float4*>(A + (size_t)row0 * HD);
    #pragma unroll
    for (int q = 0; q < 12; ++q) {
        const int f4 = t + q * 256;
        const int r = f4 / 48, c = f4 % 48;
        *reinterpret_cast<float4*>(&xs[r][c * 4]) = ap[f4];
    }

    const int tr = t >> 4;
    const int tc = t & 15;
    float acc[4][12];
    #pragma unroll
    for (int i = 0; i < 4; ++i)
        #pragma unroll
        for (int j = 0; j < 12; ++j) acc[i][j] = 0.f;

    for (int kc = 0; kc < 6; ++kc) {
        __syncthreads();
        {
            const float4* wp = reinterpret_cast<const float4*>(W + kc * 32 * HD);
            float4* wsp = reinterpret_cast<float4*>(&wchunk[0][0]);
            #pragma unroll
            for (int q = 0; q < 6; ++q) wsp[t + q * 256] = wp[t + q * 256];
        }
        __syncthreads();
        #pragma unroll 4
        for (int k = 0; k < 32; ++k) {
            const int kg = kc * 32 + k;
            float xv[4];
            #pragma unroll
            for (int i = 0; i < 4; ++i) xv[i] = xs[tr * 4 + i][kg];
            float wv[12];
            #pragma unroll
            for (int j4 = 0; j4 < 3; ++j4)
                *reinterpret_cast<float4*>(&wv[j4 * 4]) =
                    *reinterpret_cast<const float4*>(&wchunk[k][tc * 12 + j4 * 4]);
            #pragma unroll
            for (int i = 0; i < 4; ++i)
                #pragma unroll
                for (int j = 0; j < 12; ++j)
                    acc[i][j] = fmaf(xv[i], wv[j], acc[i][j]);
        }
    }

    float bb[12];
    #pragma unroll
    for (int j = 0; j < 12; ++j) bb[j] = bias[tc * 12 + j];

    #pragma unroll
    for (int i = 0; i < 4; ++i) {
        float* o = out + (size_t)(row0 + tr * 4 + i) * HD + tc * 12;
        #pragma unroll
        for (int j4 = 0; j4 < 3; ++j4) {
            float4 v;
            v.x = acc[i][j4 * 4 + 0] + bb[j4 * 4 + 0];
            v.y = acc[i][j4 * 4 + 1] + bb[j4 * 4 + 1];
            v.z = acc[i][j4 * 4 + 2] + bb[j4 * 4 + 2];
            v.w = acc[i][j4 * 4 + 3] + bb[j4 * 4 + 3];
            *reinterpret_cast<float4*>(o + j4 * 4) = v;
        }
    }
}

extern "C" void kernel_launch(void* const* d_in, const int* in_sizes, int n_in,
                              void* d_out, int out_size, void* d_ws, size_t ws_size,
                              hipStream_t stream)
{
    const float* feat = (const float*)d_in[0];
    const float* pos  = (const float*)d_in[1];
    const int*   sup  = (const int*)d_in[2];
    const int*   src  = (const int*)d_in[4];
    const float* Win  = (const float*)d_in[6];
    const float* bin  = (const float*)d_in[7];
    const float* W1   = (const float*)d_in[8];   // [384,192]
    const float* b1   = (const float*)d_in[9];
    const float* W2   = (const float*)d_in[10];  // [192,192]
    const float* b2   = (const float*)d_in[11];

    char* ws = (char*)d_ws;
    __hip_bfloat16* a  = (__hip_bfloat16*)ws;                       // 100663296 B
    float*          b  = (float*)(ws + 100663296);                  //  12582912 B
    float*          g  = b;                                         //  in-place
    __hip_bfloat16* Wt = (__hip_bfloat16*)(ws + 113246208);         //     73728 B
    float* out = (float*)d_out;

    // W1_top -> bf16 transposed
    prep_wt_kernel<<<144, 256, 0, stream>>>(W1, Wt);
    // a = x @ W1_top  (bf16 MFMA)
    a_mfma_kernel<<<N_NODES / 64, 256, 0, stream>>>(feat, pos, Win, bin, Wt, a);
    // b = x[sup] @ W1_bot + b1  (f32)
    x_gemm_kernel<true, false, true><<<N_SUP / 64, 256, 0, stream>>>(
        feat, pos, sup, Win, bin, W1 + 192 * HD, b1, (void*)b);
    // g = segment-mean(gelu(a[src] + b[dst]))   (g aliases b)
    pool_kernel<<<N_SUP / 2, 192, 0, stream>>>(a, b, src, g);
    // out = g @ W2 + b2
    gemm192_kernel<<<N_SUP / 64, 256, 0, stream>>>(g, W2, b2, out);
}

// Round 3
// 325.464 us; speedup vs baseline: 1.5742x; 1.0370x over previous
//
#include <hip/hip_runtime.h>
#include <hip/hip_bf16.h>

// SupernodePooling, restructured:
//   x = feat@W_in + b_in + sincos(pos)            [N,192]   (never materialized)
//   a = x @ W1_top                                [N,192]   bf16 in ws   (MFMA bf16)
//   b = x[sup] @ W1_bot + b1                      [S,192]   bf16, interleaved in C
//   g[s] = mean_{e} gelu(a[src_e] + b[s])         [S,192]   f32, overwrites C in place
//   out = g @ W2 + b2                             [S,192]   f32
// Valid because concat-GEMM splits and segment-mean commutes with W2.
// Edge e belongs to segment e/32 (dst_idx = repeat(sorted supernode_idxs, 32)).

#define HD 192
#define INF 16
#define N_NODES 262144
#define N_SUP 16384
#define XS_STRIDE 232   // bf16 units; 464 B rows: 16B-aligned, bank-spread
#define A_TILES 4

typedef __attribute__((ext_vector_type(8))) short bf16x8;
typedef __attribute__((ext_vector_type(4))) float f32x4;

__device__ __forceinline__ unsigned f2bf(float f) {
    unsigned x = __float_as_uint(f);
    return (x + 0x7fffu + ((x >> 16) & 1u)) >> 16;   // RNE to bf16
}
__device__ __forceinline__ float bf2f(unsigned short u) {
    return __uint_as_float(((unsigned)u) << 16);
}

// ---------------------------------------------------------------------------
// prep: Wt[n][k]=bf16(W1top[k][n]); Wb[n][k]=bf16(W1bot[k][n]); Wint[c][k]=Win[k][c]
// ---------------------------------------------------------------------------
__global__ void prep_kernel(const float* __restrict__ W1,
                            const float* __restrict__ Win,
                            unsigned short* __restrict__ Wt,
                            unsigned short* __restrict__ Wb,
                            float* __restrict__ Wint)
{
    const int i = blockIdx.x * 256 + threadIdx.x;
    if (i < 36864) {
        const int n = i / HD, k = i % HD;
        Wt[i] = (unsigned short)f2bf(W1[k * HD + n]);
    } else if (i < 73728) {
        const int j = i - 36864;
        const int n = j / HD, k = j % HD;
        Wb[j] = (unsigned short)f2bf(W1[(size_t)(HD + k) * HD + n]);
    } else if (i < 76800) {
        const int j = i - 73728;
        const int c = j / INF, k = j % INF;
        Wint[j] = Win[k * HD + c];
    }
}

// ---------------------------------------------------------------------------
// Per-wave stage: load feat (16B/lane) + pos (4B/lane, l<48) for 16 rows.
// ---------------------------------------------------------------------------
template<bool GATHER>
__device__ __forceinline__ void stage_load(const float* __restrict__ feat,
                                           const float* __restrict__ pos,
                                           const int* __restrict__ gidx,
                                           int row0w, int l,
                                           float4& fstage, float& pstage)
{
    if (GATHER) {
        const int nid = gidx[row0w + (l & 15)];
        const int frow = __shfl(nid, l >> 2);
        fstage = *reinterpret_cast<const float4*>(feat + (size_t)frow * INF + (l & 3) * 4);
        const int prow = __shfl(nid, (l < 48 ? l : 47) / 3);
        if (l < 48) pstage = pos[(size_t)prow * 3 + (l % 3)];
    } else {
        fstage = *reinterpret_cast<const float4*>(feat + (size_t)(row0w + (l >> 2)) * INF + (l & 3) * 4);
        if (l < 48) pstage = pos[(size_t)row0w * 3 + l];
    }
}

// ---------------------------------------------------------------------------
// out[row] = bf16( (x[row or gidx[row]]) @ Wt^T (+bias) )  via mfma 16x16x32
// 4 waves: wave w -> output cols [w*48, w*48+48), all 64 rows of the tile.
// A-frag: lane row (l&15), k=(l>>4)*8+i ; B-frag: col (l&15), same k
// D: col=l&15, row=(l>>4)*4+reg  (layout proven in round 2)
// 2 barriers per tile; next-tile feat/pos prefetched into regs during MFMA.
// ---------------------------------------------------------------------------
template<bool GATHER>
__global__ __launch_bounds__(256, 2)
void xw_mfma_kernel(const float* __restrict__ feat,   // [N,16]
                    const float* __restrict__ pos,    // [N,3]
                    const int*   __restrict__ gidx,   // [rows] or null
                    const float* __restrict__ Wint,   // [192 c][16 k] f32
                    const float* __restrict__ bin,    // [192]
                    const unsigned short* __restrict__ Wt,  // [192 n][192 k] bf16
                    const float* __restrict__ bias,   // [192] or null
                    unsigned short* __restrict__ outp,
                    int out_stride,                   // elems: 192 (a) or 384 (C)
                    int ntiles)
{
    __shared__ __align__(16) unsigned short xs[64 * XS_STRIDE];   // 29696 B
    __shared__ __align__(16) unsigned short dstg[64 * XS_STRIDE]; // 29696 B
    __shared__ __align__(16) float feat_s[4 * 256];               // 4096 B
    __shared__ float pos_s[4 * 48];                               //  768 B

    const int t = threadIdx.x;
    const int w = t >> 6, l = t & 63;

    // --- persistent preloads ---
    bf16x8 bf[3][6];
    #pragma unroll
    for (int ct = 0; ct < 3; ++ct) {
        const int col = w * 48 + ct * 16 + (l & 15);
        const unsigned short* wp = Wt + (size_t)col * HD + (l >> 4) * 8;
        #pragma unroll
        for (int ks = 0; ks < 6; ++ks)
            bf[ct][ks] = *reinterpret_cast<const bf16x8*>(wp + ks * 32);
    }
    float win[3][INF];
    #pragma unroll
    for (int d = 0; d < 3; ++d)
        #pragma unroll
        for (int q = 0; q < 4; ++q)
            *reinterpret_cast<float4*>(&win[d][q * 4]) =
                *reinterpret_cast<const float4*>(Wint + (size_t)(l + 64 * d) * INF + q * 4);
    float bcol[3];
    #pragma unroll
    for (int d = 0; d < 3; ++d) bcol[d] = bin[l + 64 * d];
    float bias_c[3] = {0.f, 0.f, 0.f};
    if (GATHER) {
        #pragma unroll
        for (int ct = 0; ct < 3; ++ct) bias_c[ct] = bias[w * 48 + ct * 16 + (l & 15)];
    }
    const float om = exp2f(-(float)(l & 31) * 0.41524101186098287f);
    const bool is_sin = (l < 32);

    // --- prologue: stage tile 0 into regs ---
    float4 fstage; float pstage = 0.f;
    stage_load<GATHER>(feat, pos, gidx, blockIdx.x * ntiles * 64 + w * 16, l, fstage, pstage);

    for (int tt = 0; tt < ntiles; ++tt) {
        const int tile_row0 = (blockIdx.x * ntiles + tt) * 64;

        // regs -> wave-local LDS (compiler inserts vmcnt/lgkmcnt as needed)
        *reinterpret_cast<float4*>(&feat_s[w * 256 + l * 4]) = fstage;
        if (l < 48) pos_s[w * 48 + l] = pstage;

        // x-compute: wave w fills rows w*16..w*16+15, cols {l, l+64, l+128}
        for (int r = 0; r < 16; ++r) {
            const int n = w * 16 + r;
            float fr[INF];
            #pragma unroll
            for (int q = 0; q < 4; ++q)
                *reinterpret_cast<float4*>(&fr[q * 4]) =
                    *reinterpret_cast<const float4*>(&feat_s[w * 256 + r * 16 + q * 4]);
            #pragma unroll
            for (int d = 0; d < 3; ++d) {
                const float ang = pos_s[w * 48 + r * 3 + d] * om;
                const float pe  = is_sin ? __sinf(ang) : __cosf(ang);
                float acc = bcol[d] + pe;
                #pragma unroll
                for (int k = 0; k < INF; ++k) acc = fmaf(fr[k], win[d][k], acc);
                xs[n * XS_STRIDE + l + 64 * d] = (unsigned short)f2bf(acc);
            }
        }
        __syncthreads();   // bar1: xs ready for all waves

        // prefetch next tile's feat/pos into regs (latency hides under MFMA)
        if (!GATHER && tt + 1 < ntiles)
            stage_load<false>(feat, pos, gidx, tile_row0 + 64 + w * 16, l, fstage, pstage);

        // MFMA: 4 row-tiles x 3 col-tiles, K = 6 x 32
        f32x4 acc[4][3];
        #pragma unroll
        for (int rt = 0; rt < 4; ++rt)
            #pragma unroll
            for (int ct = 0; ct < 3; ++ct)
                acc[rt][ct] = (f32x4){0.f, 0.f, 0.f, 0.f};
        #pragma unroll
        for (int ks = 0; ks < 6; ++ks) {
            bf16x8 af[4];
            #pragma unroll
            for (int rt = 0; rt < 4; ++rt)
                af[rt] = *reinterpret_cast<const bf16x8*>(
                    &xs[(rt * 16 + (l & 15)) * XS_STRIDE + ks * 32 + (l >> 4) * 8]);
            #pragma unroll
            for (int rt = 0; rt < 4; ++rt)
                #pragma unroll
                for (int ct = 0; ct < 3; ++ct)
                    acc[rt][ct] = __builtin_amdgcn_mfma_f32_16x16x32_bf16(
                        af[rt], bf[ct][ks], acc[rt][ct], 0, 0, 0);
        }

        // D (+bias) -> dstage (bf16)
        #pragma unroll
        for (int rt = 0; rt < 4; ++rt)
            #pragma unroll
            for (int ct = 0; ct < 3; ++ct) {
                const int col = w * 48 + ct * 16 + (l & 15);
                #pragma unroll
                for (int j = 0; j < 4; ++j) {
                    const int row = rt * 16 + (l >> 4) * 4 + j;
                    dstg[row * XS_STRIDE + col] =
                        (unsigned short)f2bf(acc[rt][ct][j] + bias_c[ct]);
                }
            }
        __syncthreads();   // bar2: dstage ready; all A-frag reads of xs done

        // coalesced store: 1536 x 16B chunks
        #pragma unroll
        for (int i = 0; i < 6; ++i) {
            const int c = t + i * 256;
            const int r = c / 24, q = c % 24;
            const bf16x8 v = *reinterpret_cast<const bf16x8*>(&dstg[r * XS_STRIDE + q * 8]);
            *reinterpret_cast<bf16x8*>(outp + (size_t)(tile_row0 + r) * out_stride + q * 8) = v;
        }
        // no trailing barrier: next x writes xs (reads of xs ended before bar2),
        // next dstg writes are after next bar1.
    }
}

// ---------------------------------------------------------------------------
// pool: g[s] = (1/32) * sum_e gelu(a[src] + b[s]); b bf16 at C+s*768B,
// g f32 overwrites the same rows (read-all-b, barrier, then write).
// block = 192 thr = 4 supernodes x 48 thr; 4 cols (ushort4, 8B) per thread.
// ---------------------------------------------------------------------------
__global__ __launch_bounds__(192)
void pool_kernel(const unsigned short* __restrict__ a,   // [N,192] bf16
                 const unsigned short* __restrict__ bC,  // rows: stride 384 elems
                 const int* __restrict__ src_idx,        // [E]
                 float* __restrict__ g)                   // rows: stride 192 f32 (same mem)
{
    __shared__ int sA[128];
    const int t = threadIdx.x;
    if (t < 128) sA[t] = src_idx[(size_t)blockIdx.x * 128 + t];
    __syncthreads();

    const int sl = t / 48;
    const int c4 = t % 48;
    const size_t s = (size_t)blockIdx.x * 4 + sl;
    const int* sp = sA + sl * 32;

    const ushort4 bu = *reinterpret_cast<const ushort4*>(bC + s * 384 + c4 * 4);
    const float b0 = bf2f(bu.x), b1v = bf2f(bu.y), b2v = bf2f(bu.z), b3v = bf2f(bu.w);

    float a0 = 0.f, a1 = 0.f, a2 = 0.f, a3 = 0.f;
    const float ir2 = 0.70710678118654752f;
    #pragma unroll 8
    for (int e = 0; e < 32; ++e) {
        const int src = sp[e];
        const ushort4 u = *reinterpret_cast<const ushort4*>(a + (size_t)src * HD + c4 * 4);
        const float v0 = bf2f(u.x) + b0;
        const float v1 = bf2f(u.y) + b1v;
        const float v2 = bf2f(u.z) + b2v;
        const float v3 = bf2f(u.w) + b3v;
        a0 += 0.5f * v0 * (1.f + erff(v0 * ir2));
        a1 += 0.5f * v1 * (1.f + erff(v1 * ir2));
        a2 += 0.5f * v2 * (1.f + erff(v2 * ir2));
        a3 += 0.5f * v3 * (1.f + erff(v3 * ir2));
    }
    __syncthreads();   // all b reads done before aliased g writes
    float4 r;
    r.x = a0 * 0.03125f; r.y = a1 * 0.03125f; r.z = a2 * 0.03125f; r.w = a3 * 0.03125f;
    *reinterpret_cast<float4*>(g + s * HD + c4 * 4) = r;
}

// ---------------------------------------------------------------------------
// out = A[rows,192] @ W[192,192] + bias   (f32)
// ---------------------------------------------------------------------------
__global__ __launch_bounds__(256, 2)
void gemm192_kernel(const float* __restrict__ A,
                    const float* __restrict__ W,
                    const float* __restrict__ bias,
                    float* __restrict__ out)
{
    __shared__ float xsf[64][196];
    __shared__ float wchunk[32][HD];
    const int t    = threadIdx.x;
    const int row0 = blockIdx.x * 64;

    const float4* ap = reinterpret_cast<const float4*>(A + (size_t)row0 * HD);
    #pragma unroll
    for (int q = 0; q < 12; ++q) {
        const int f4 = t + q * 256;
        const int r = f4 / 48, c = f4 % 48;
        *reinterpret_cast<float4*>(&xsf[r][c * 4]) = ap[f4];
    }

    const int tr = t >> 4;
    const int tc = t & 15;
    float acc[4][12];
    #pragma unroll
    for (int i = 0; i < 4; ++i)
        #pragma unroll
        for (int j = 0; j < 12; ++j) acc[i][j] = 0.f;

    for (int kc = 0; kc < 6; ++kc) {
        __syncthreads();
        {
            const float4* wp = reinterpret_cast<const float4*>(W + kc * 32 * HD);
            float4* wsp = reinterpret_cast<float4*>(&wchunk[0][0]);
            #pragma unroll
            for (int q = 0; q < 6; ++q) wsp[t + q * 256] = wp[t + q * 256];
        }
        __syncthreads();
        #pragma unroll 4
        for (int k = 0; k < 32; ++k) {
            const int kg = kc * 32 + k;
            float xv[4];
            #pragma unroll
            for (int i = 0; i < 4; ++i) xv[i] = xsf[tr * 4 + i][kg];
            float wv[12];
            #pragma unroll
            for (int j4 = 0; j4 < 3; ++j4)
                *reinterpret_cast<float4*>(&wv[j4 * 4]) =
                    *reinterpret_cast<const float4*>(&wchunk[k][tc * 12 + j4 * 4]);
            #pragma unroll
            for (int i = 0; i < 4; ++i)
                #pragma unroll
                for (int j = 0; j < 12; ++j)
                    acc[i][j] = fmaf(xv[i], wv[j], acc[i][j]);
        }
    }

    float bb[12];
    #pragma unroll
    for (int j = 0; j < 12; ++j) bb[j] = bias[tc * 12 + j];

    #pragma unroll
    for (int i = 0; i < 4; ++i) {
        float* o = out + (size_t)(row0 + tr * 4 + i) * HD + tc * 12;
        #pragma unroll
        for (int j4 = 0; j4 < 3; ++j4) {
            float4 v;
            v.x = acc[i][j4 * 4 + 0] + bb[j4 * 4 + 0];
            v.y = acc[i][j4 * 4 + 1] + bb[j4 * 4 + 1];
            v.z = acc[i][j4 * 4 + 2] + bb[j4 * 4 + 2];
            v.w = acc[i][j4 * 4 + 3] + bb[j4 * 4 + 3];
            *reinterpret_cast<float4*>(o + j4 * 4) = v;
        }
    }
}

extern "C" void kernel_launch(void* const* d_in, const int* in_sizes, int n_in,
                              void* d_out, int out_size, void* d_ws, size_t ws_size,
                              hipStream_t stream)
{
    const float* feat = (const float*)d_in[0];
    const float* pos  = (const float*)d_in[1];
    const int*   sup  = (const int*)d_in[2];
    const int*   src  = (const int*)d_in[4];
    const float* Win  = (const float*)d_in[6];
    const float* bin  = (const float*)d_in[7];
    const float* W1   = (const float*)d_in[8];   // [384,192]
    const float* b1   = (const float*)d_in[9];
    const float* W2   = (const float*)d_in[10];  // [192,192]
    const float* b2   = (const float*)d_in[11];

    char* ws = (char*)d_ws;
    unsigned short* Wt   = (unsigned short*)ws;                 //  73728 B
    unsigned short* Wb   = (unsigned short*)(ws + 73728);       //  73728 B
    float*          Wint = (float*)(ws + 147456);               //  12288 B
    unsigned short* a    = (unsigned short*)(ws + 159744);      // 100663296 B
    char*           C    = ws + 159744 + 100663296;             //  12582912 B
    float* out = (float*)d_out;

    prep_kernel<<<300, 256, 0, stream>>>(W1, Win, Wt, Wb, Wint);

    // a = x @ W1_top  (bf16), 1024 blocks x 4 tiles, prefetch-pipelined
    xw_mfma_kernel<false><<<N_NODES / (64 * A_TILES), 256, 0, stream>>>(
        feat, pos, nullptr, Wint, bin, Wt, nullptr, a, HD, A_TILES);
    // b = x[sup] @ W1_bot + b1  (bf16, interleaved rows at stride 384 elems)
    xw_mfma_kernel<true><<<N_SUP / 64, 256, 0, stream>>>(
        feat, pos, sup, Wint, bin, Wb, b1, (unsigned short*)C, 384, 1);
    // g = segment-mean(gelu(a[src] + b[dst]))  (overwrites C rows with f32)
    pool_kernel<<<N_SUP / 4, 192, 0, stream>>>(a, (const unsigned short*)C, src, (float*)C);
    // out = g @ W2 + b2
    gemm192_kernel<<<N_SUP / 64, 256, 0, stream>>>((const float*)C, W2, b2, out);
}